// Round 8
// baseline (312.790 us; speedup 1.0000x reference)
//
#include <hip/hip_runtime.h>

#define NB 4
#define HWN 4096
#define CD 64
#define NSTRIDE (HWN * CD)  // 262144 elems per batch in all swizzled buffers

typedef short short8 __attribute__((ext_vector_type(8), may_alias));
typedef float f32x4 __attribute__((ext_vector_type(4), may_alias));

__device__ constexpr float C1 = 0.18033688011112042f; // log2(e)/8

__device__ __forceinline__ unsigned short f2bf(float f) {
    unsigned u = __builtin_bit_cast(unsigned, f);
    u = (u + 0x7FFFu + ((u >> 16) & 1u)) >> 16;  // RTN-even
    return (unsigned short)u;
}

__device__ __forceinline__ float fexp2(float x) {
#if __has_builtin(__builtin_amdgcn_exp2f)
    return __builtin_amdgcn_exp2f(x);
#else
    return exp2f(x);
#endif
}

// async global->LDS DMA, 16B/lane: dst = uniform LDS base (+lane*16 implicit),
// src = per-lane global pointer. Tracked by vmcnt; drained by __syncthreads.
__device__ __forceinline__ void gload_lds16(const unsigned short* g, unsigned short* lds) {
    __builtin_amdgcn_global_load_lds(
        (const __attribute__((address_space(1))) unsigned int*)g,
        (__attribute__((address_space(3))) unsigned int*)lds, 16, 0, 0);
}

// Frag-major swizzle for a row-major [R][64] matrix, 16-row tiles:
// elem(row, c) -> tile = row>>4, half = c>>5, lane l = ((c>>3)&3)*16 + (row&15),
// offset = tile*1024 + half*512 + l*8 + (c&7).
__device__ __forceinline__ size_t qk_swz(int row, int c) {
    return (size_t)(row >> 4) * 1024 + (c >> 5) * 512 +
           ((((c >> 3) & 3) * 16 + (row & 15)) * 8) + (c & 7);
}

// ---------- prep: Q,K fp32 -> bf16, frag-major swizzled ----------
__global__ __launch_bounds__(256) void cvt_qk(const float* __restrict__ Q,
                                              const float* __restrict__ K,
                                              unsigned short* __restrict__ Qs,
                                              unsigned short* __restrict__ Ks) {
    int i = (blockIdx.x * 256 + threadIdx.x) * 4;
    int rg = i >> 6, c = i & 63;
    int n = rg >> 12, r = rg & 4095;
    float4 q = *(const float4*)(Q + i);
    float4 k = *(const float4*)(K + i);
    ushort4 qo, ko;
    qo.x = f2bf(q.x); qo.y = f2bf(q.y); qo.z = f2bf(q.z); qo.w = f2bf(q.w);
    ko.x = f2bf(k.x); ko.y = f2bf(k.y); ko.z = f2bf(k.z); ko.w = f2bf(k.w);
    size_t off = (size_t)n * NSTRIDE + qk_swz(r, c);
    *(ushort4*)(Qs + off) = qo;
    *(ushort4*)(Ks + off) = ko;
}

// ---------- phase 1: l[n,k] = sum_q exp2(C1 * dot(Q[q],K[k])) ----------
// Block: 4 waves x 32 stationary k = 128 k; Q streamed through double-buffered
// LDS via global_load_lds DMA (issued post-barrier, drained at next barrier).
// grid (32 k-blocks of 128, NB, 16 q-slices of 256).
__global__ __launch_bounds__(256, 8) void lsum_kernel(const unsigned short* __restrict__ Qs,
                                                      const unsigned short* __restrict__ Ks,
                                                      float* __restrict__ l) {
    __shared__ unsigned short qstage[2][1024];  // 16q x 64c per buffer
    int tid = threadIdx.x;
    int w = tid >> 6, lane = tid & 63, quad = lane >> 4, m16 = lane & 15;
    int n = blockIdx.y;
    int kbase = blockIdx.x * 128 + w * 32;

    const unsigned short* Kp = Ks + (size_t)n * NSTRIDE + (kbase >> 4) * 1024 + lane * 8;
    short8 ka0 = *(const short8*)(Kp);
    short8 ka1 = *(const short8*)(Kp + 512);
    short8 kb0 = *(const short8*)(Kp + 1024);
    short8 kb1 = *(const short8*)(Kp + 1536);

    const unsigned short* Qsrc = Qs + (size_t)n * NSTRIDE + blockIdx.z * 16384;

    // prologue: stage Q tile 0 (waves 0,1 each move 1 KB)
    if (w < 2) gload_lds16(Qsrc + w * 512 + lane * 8, &qstage[0][w * 512]);

    float lA[4] = {0.f, 0.f, 0.f, 0.f};
    float lB[4] = {0.f, 0.f, 0.f, 0.f};
    for (int it = 0; it < 16; ++it) {
        __syncthreads();  // drains DMA(it) (vmcnt(0) before s_barrier) for all waves
        if (it + 1 < 16 && w < 2)
            gload_lds16(Qsrc + (it + 1) * 1024 + w * 512 + lane * 8,
                        &qstage[(it + 1) & 1][w * 512]);
        short8 qf0 = *(const short8*)&qstage[it & 1][lane * 8];
        short8 qf1 = *(const short8*)&qstage[it & 1][512 + lane * 8];
        f32x4 a = {0.f, 0.f, 0.f, 0.f}, b = {0.f, 0.f, 0.f, 0.f};
        a = __builtin_amdgcn_mfma_f32_16x16x32_bf16(ka0, qf0, a, 0, 0, 0);
        a = __builtin_amdgcn_mfma_f32_16x16x32_bf16(ka1, qf1, a, 0, 0, 0);
        b = __builtin_amdgcn_mfma_f32_16x16x32_bf16(kb0, qf0, b, 0, 0, 0);
        b = __builtin_amdgcn_mfma_f32_16x16x32_bf16(kb1, qf1, b, 0, 0, 0);
#pragma unroll
        for (int r = 0; r < 4; ++r) {
            lA[r] += fexp2(a[r] * C1);
            lB[r] += fexp2(b[r] * C1);
        }
    }
#pragma unroll
    for (int r = 0; r < 4; ++r)
        for (int d = 1; d < 16; d <<= 1) {
            lA[r] += __shfl_xor(lA[r], d);
            lB[r] += __shfl_xor(lB[r], d);
        }
    if (m16 == 0) {
        float* lp = l + n * HWN + kbase + quad * 4;
#pragma unroll
        for (int r = 0; r < 4; ++r) {
            atomicAdd(lp + r, lA[r]);
            atomicAdd(lp + 16 + r, lB[r]);
        }
    }
}

// ---------- prep: Vts = frag-major bf16(V[n][k][c] / l[n][k]), [c][k]-tiled ----------
__global__ __launch_bounds__(256) void prep_v(const float* __restrict__ V,
                                              const float* __restrict__ l,
                                              unsigned short* __restrict__ Vts) {
    __shared__ float rl[64];
    __shared__ float tile[64][65];
    int tid = threadIdx.x, n = blockIdx.y, kbase = blockIdx.x * 64;
    if (tid < 64) rl[tid] = 1.0f / l[n * HWN + kbase + tid];
    __syncthreads();
#pragma unroll
    for (int i = 0; i < 16; ++i) {
        int e = i * 256 + tid;
        int k = e >> 6, c = e & 63;
        tile[c][k] = V[((size_t)(n * HWN + kbase + k)) * CD + c] * rl[k];
    }
    __syncthreads();
#pragma unroll
    for (int i = 0; i < 2; ++i) {
        int s = i * 256 + tid;
        int c = s >> 3, kg = s & 7;
        int kl = kg * 8;
        int kgl = kbase + kl;
        short8 v;
#pragma unroll
        for (int j = 0; j < 8; ++j) v[j] = (short)f2bf(tile[c][kl + j]);
        size_t off = (size_t)n * NSTRIDE + (size_t)(kgl >> 5) * 2048 + (c >> 4) * 512 +
                     ((((kgl >> 3) & 3) * 16 + (c & 15)) * 8);
        *(short8*)(Vts + off) = v;
    }
}

// ---------- phase 2: out[q,c] = sum_k exp2(C1*s_qk) * V[k][c]/l[k] ----------
// Block: 4 waves x 32 q = 128 q, sharing one K/V stream staged in LDS (8 KB/iter,
// double-buffered, global_load_lds). P and V consumed one iteration late
// (P via per-wave dbuf LDS, V in registers) so no in-iter DS round-trip stall.
// grid (32 q-blocks of 128, NB, ns k-slices).
__global__ __launch_bounds__(256, 4) void attn_kernel(const unsigned short* __restrict__ Qs,
                                                      const unsigned short* __restrict__ Ks,
                                                      const unsigned short* __restrict__ Vts,
                                                      float* __restrict__ partial,
                                                      int nit) {
    __shared__ unsigned short stage[2][4096];   // [buf][ K 2048 | V 2048 ] shorts
    __shared__ short plds[4][2][2][16][40];     // [wave][pbuf][qtile][row][col]
    int tid = threadIdx.x;
    int w = tid >> 6, lane = tid & 63, quad = lane >> 4, m16 = lane & 15;
    int n = blockIdx.y;
    int qbase = blockIdx.x * 128 + w * 32;

    const unsigned short* Qp = Qs + (size_t)n * NSTRIDE + (qbase >> 4) * 1024 + lane * 8;
    short8 qa0 = *(const short8*)(Qp);
    short8 qa1 = *(const short8*)(Qp + 512);
    short8 qb0 = *(const short8*)(Qp + 1024);
    short8 qb1 = *(const short8*)(Qp + 1536);

    size_t kofs = (size_t)blockIdx.z * (size_t)nit * 2048;
    const unsigned short* Ksrc = Ks + (size_t)n * NSTRIDE + kofs;
    const unsigned short* Vsrc = Vts + (size_t)n * NSTRIDE + kofs;
    // wave w stages shorts [w*1024, w*1024+1024) of the 4096-short tile (2 instr)
    const unsigned short* dsrc0 = (w < 2) ? (Ksrc + w * 1024) : (Vsrc + (w - 2) * 1024);

    f32x4 oA[4], oB[4];
#pragma unroll
    for (int ct = 0; ct < 4; ++ct) { oA[ct] = f32x4{0.f, 0.f, 0.f, 0.f}; oB[ct] = oA[ct]; }

    int wr = quad * 4 * 40 + m16;   // P store base within a qtile buffer
    int rd = m16 * 40 + quad * 8;   // P A-frag read base

    short8 vp0, vp1, vp2, vp3;      // V(it-1) carried in registers

    // prologue: stage tile 0
    gload_lds16(dsrc0 + lane * 8, &stage[0][w * 1024]);
    gload_lds16(dsrc0 + 512 + lane * 8, &stage[0][w * 1024 + 512]);

    for (int it = 0; it < nit; ++it) {
        __syncthreads();  // drains DMA(it) for ALL waves (vmcnt(0) before s_barrier)
        if (it + 1 < nit) {
            const unsigned short* ds = dsrc0 + (it + 1) * 2048;
            unsigned short* dd = &stage[(it + 1) & 1][w * 1024];
            gload_lds16(ds + lane * 8, dd);
            gload_lds16(ds + 512 + lane * 8, dd + 512);
        }
        const unsigned short* kb = &stage[it & 1][0];
        const unsigned short* vb = &stage[it & 1][2048];

        // K frags (LDS, conflict-free b128) + S-MFMAs for both q-tiles
        short8 kf00 = *(const short8*)(kb + lane * 8);
        short8 kf01 = *(const short8*)(kb + 512 + lane * 8);
        short8 kf10 = *(const short8*)(kb + 1024 + lane * 8);
        short8 kf11 = *(const short8*)(kb + 1536 + lane * 8);
        f32x4 sA0 = {0.f, 0.f, 0.f, 0.f}, sA1 = sA0, sB0 = sA0, sB1 = sA0;
        sA0 = __builtin_amdgcn_mfma_f32_16x16x32_bf16(qa0, kf00, sA0, 0, 0, 0);
        sA0 = __builtin_amdgcn_mfma_f32_16x16x32_bf16(qa1, kf01, sA0, 0, 0, 0);
        sA1 = __builtin_amdgcn_mfma_f32_16x16x32_bf16(qa0, kf10, sA1, 0, 0, 0);
        sA1 = __builtin_amdgcn_mfma_f32_16x16x32_bf16(qa1, kf11, sA1, 0, 0, 0);
        sB0 = __builtin_amdgcn_mfma_f32_16x16x32_bf16(qb0, kf00, sB0, 0, 0, 0);
        sB0 = __builtin_amdgcn_mfma_f32_16x16x32_bf16(qb1, kf01, sB0, 0, 0, 0);
        sB1 = __builtin_amdgcn_mfma_f32_16x16x32_bf16(qb0, kf10, sB1, 0, 0, 0);
        sB1 = __builtin_amdgcn_mfma_f32_16x16x32_bf16(qb1, kf11, sB1, 0, 0, 0);

        // PV for it-1: P(it-1) from per-wave LDS dbuf, V(it-1) from registers
        if (it > 0) {
            int pb = (it - 1) & 1;
            short8 pfA = *(const short8*)(&plds[w][pb][0][0][0] + rd);
            short8 pfB = *(const short8*)(&plds[w][pb][1][0][0] + rd);
            oA[0] = __builtin_amdgcn_mfma_f32_16x16x32_bf16(pfA, vp0, oA[0], 0, 0, 0);
            oA[1] = __builtin_amdgcn_mfma_f32_16x16x32_bf16(pfA, vp1, oA[1], 0, 0, 0);
            oA[2] = __builtin_amdgcn_mfma_f32_16x16x32_bf16(pfA, vp2, oA[2], 0, 0, 0);
            oA[3] = __builtin_amdgcn_mfma_f32_16x16x32_bf16(pfA, vp3, oA[3], 0, 0, 0);
            oB[0] = __builtin_amdgcn_mfma_f32_16x16x32_bf16(pfB, vp0, oB[0], 0, 0, 0);
            oB[1] = __builtin_amdgcn_mfma_f32_16x16x32_bf16(pfB, vp1, oB[1], 0, 0, 0);
            oB[2] = __builtin_amdgcn_mfma_f32_16x16x32_bf16(pfB, vp2, oB[2], 0, 0, 0);
            oB[3] = __builtin_amdgcn_mfma_f32_16x16x32_bf16(pfB, vp3, oB[3], 0, 0, 0);
        }

        // P(it) = exp2(C1*S) -> per-wave LDS dbuf (C-layout row=q, col=k)
        {
            int pb = it & 1;
            short* pA = &plds[w][pb][0][0][0] + wr;
            short* pB = &plds[w][pb][1][0][0] + wr;
#pragma unroll
            for (int r = 0; r < 4; ++r) {
                pA[r * 40]      = (short)f2bf(fexp2(sA0[r] * C1));
                pA[r * 40 + 16] = (short)f2bf(fexp2(sA1[r] * C1));
                pB[r * 40]      = (short)f2bf(fexp2(sB0[r] * C1));
                pB[r * 40 + 16] = (short)f2bf(fexp2(sB1[r] * C1));
            }
        }

        // V(it) frags -> registers for next iteration's PV
        vp0 = *(const short8*)(vb + lane * 8);
        vp1 = *(const short8*)(vb + 512 + lane * 8);
        vp2 = *(const short8*)(vb + 1024 + lane * 8);
        vp3 = *(const short8*)(vb + 1536 + lane * 8);
    }

    // epilogue: PV for it = nit-1
    {
        int pb = (nit - 1) & 1;
        short8 pfA = *(const short8*)(&plds[w][pb][0][0][0] + rd);
        short8 pfB = *(const short8*)(&plds[w][pb][1][0][0] + rd);
        oA[0] = __builtin_amdgcn_mfma_f32_16x16x32_bf16(pfA, vp0, oA[0], 0, 0, 0);
        oA[1] = __builtin_amdgcn_mfma_f32_16x16x32_bf16(pfA, vp1, oA[1], 0, 0, 0);
        oA[2] = __builtin_amdgcn_mfma_f32_16x16x32_bf16(pfA, vp2, oA[2], 0, 0, 0);
        oA[3] = __builtin_amdgcn_mfma_f32_16x16x32_bf16(pfA, vp3, oA[3], 0, 0, 0);
        oB[0] = __builtin_amdgcn_mfma_f32_16x16x32_bf16(pfB, vp0, oB[0], 0, 0, 0);
        oB[1] = __builtin_amdgcn_mfma_f32_16x16x32_bf16(pfB, vp1, oB[1], 0, 0, 0);
        oB[2] = __builtin_amdgcn_mfma_f32_16x16x32_bf16(pfB, vp2, oB[2], 0, 0, 0);
        oB[3] = __builtin_amdgcn_mfma_f32_16x16x32_bf16(pfB, vp3, oB[3], 0, 0, 0);
    }

    // o{A,B}[ct][r] = O_partial[q][c = ct*16 + m16]; plain stores
    float* pp = partial + (size_t)blockIdx.z * (NB * HWN * CD) +
                ((size_t)(n * HWN + qbase + quad * 4)) * CD + m16;
#pragma unroll
    for (int ct = 0; ct < 4; ++ct)
#pragma unroll
        for (int r = 0; r < 4; ++r) {
            pp[r * CD + ct * 16] = oA[ct][r];
            pp[(16 + r) * CD + ct * 16] = oB[ct][r];
        }
}

// ---------- final: out = sum of ns partial slices ----------
__global__ __launch_bounds__(256) void reduce_out(const float* __restrict__ p,
                                                  float* __restrict__ out, int ns) {
    int i = (blockIdx.x * 256 + threadIdx.x) * 4;
    f32x4 a = *(const f32x4*)(p + i);
    for (int s = 1; s < ns; ++s)
        a = a + *(const f32x4*)(p + (size_t)s * (NB * HWN * CD) + i);
    *(f32x4*)(out + i) = a;
}

extern "C" void kernel_launch(void* const* d_in, const int* in_sizes, int n_in,
                              void* d_out, int out_size, void* d_ws, size_t ws_size,
                              hipStream_t stream) {
    const float* Q = (const float*)d_in[0];
    const float* K = (const float*)d_in[1];
    const float* V = (const float*)d_in[2];
    float* out = (float*)d_out;

    char* ws = (char*)d_ws;
    unsigned short* Qs  = (unsigned short*)(ws);                   // 2 MB
    unsigned short* Ks  = (unsigned short*)(ws + (1u << 21));      // 2 MB
    unsigned short* Vts = (unsigned short*)(ws + (2u << 21));      // 2 MB
    float* l       = (float*)(ws + (3u << 21));                    // 64 KB
    float* partial = (float*)(ws + (4u << 21));                    // ns * 4 MB

    size_t base = (size_t)(4u << 21);
    size_t slice = (size_t)NB * HWN * CD * sizeof(float);
    int ns = (ws_size >= base + 8 * slice) ? 8
           : (ws_size >= base + 4 * slice) ? 4 : 2;
    int nit = HWN / ns / 32;  // 32-k steps per block: ns=8 -> 16

    hipMemsetAsync(l, 0, (size_t)NB * HWN * sizeof(float), stream);

    cvt_qk<<<1024, 256, 0, stream>>>(Q, K, Qs, Ks);
    lsum_kernel<<<dim3(32, NB, 16), 256, 0, stream>>>(Qs, Ks, l);
    prep_v<<<dim3(64, NB), 256, 0, stream>>>(V, l, Vts);
    attn_kernel<<<dim3(32, NB, ns), 256, 0, stream>>>(Qs, Ks, Vts, partial, nit);
    reduce_out<<<1024, 256, 0, stream>>>(partial, out, ns);
}

// Round 10
// 142.002 us; speedup vs baseline: 2.2027x; 2.2027x over previous
//
#include <hip/hip_runtime.h>

#define NB 4
#define HWN 4096
#define CD 64
#define NSTRIDE (HWN * CD)  // 262144 elems per batch in all swizzled buffers

typedef short short8 __attribute__((ext_vector_type(8), may_alias));
typedef float f32x4 __attribute__((ext_vector_type(4), may_alias));

__device__ constexpr float C1 = 0.18033688011112042f; // log2(e)/8 (folded into Qs)

__device__ __forceinline__ unsigned short f2bf(float f) {
    unsigned u = __builtin_bit_cast(unsigned, f);
    u = (u + 0x7FFFu + ((u >> 16) & 1u)) >> 16;  // RTN-even
    return (unsigned short)u;
}

__device__ __forceinline__ float fexp2(float x) {
#if __has_builtin(__builtin_amdgcn_exp2f)
    return __builtin_amdgcn_exp2f(x);
#else
    return exp2f(x);
#endif
}

// pack two fp32 -> bf16x2 (low = a), bitwise same rounding as f2bf
__device__ __forceinline__ unsigned pk2(float a, float b) {
    return (unsigned)f2bf(a) | ((unsigned)f2bf(b) << 16);
}

// Frag-major swizzle for a row-major [R][64] matrix, 16-row tiles:
// elem(row, c) -> tile = row>>4, half = c>>5, lane l = ((c>>3)&3)*16 + (row&15),
// offset = tile*1024 + half*512 + l*8 + (c&7).
__device__ __forceinline__ size_t qk_swz(int row, int c) {
    return (size_t)(row >> 4) * 1024 + (c >> 5) * 512 +
           ((((c >> 3) & 3) * 16 + (row & 15)) * 8) + (c & 7);
}

// ---------- prep: Qs = bf16(C1*Q) swizzled, Ks = bf16(K) swizzled ----------
__global__ __launch_bounds__(256) void cvt_qk(const float* __restrict__ Q,
                                              const float* __restrict__ K,
                                              unsigned short* __restrict__ Qs,
                                              unsigned short* __restrict__ Ks) {
    int i = (blockIdx.x * 256 + threadIdx.x) * 4;
    int rg = i >> 6, c = i & 63;
    int n = rg >> 12, r = rg & 4095;
    float4 q = *(const float4*)(Q + i);
    float4 k = *(const float4*)(K + i);
    ushort4 qo, ko;
    qo.x = f2bf(q.x * C1); qo.y = f2bf(q.y * C1);
    qo.z = f2bf(q.z * C1); qo.w = f2bf(q.w * C1);
    ko.x = f2bf(k.x); ko.y = f2bf(k.y); ko.z = f2bf(k.z); ko.w = f2bf(k.w);
    size_t off = (size_t)n * NSTRIDE + qk_swz(r, c);
    *(ushort4*)(Qs + off) = qo;
    *(ushort4*)(Ks + off) = ko;
}

// ---------- phase 1: l[n,k] = sum_q exp2(dot(C1*Q[q], K[k])) ----------
// grid (32 k-blocks of 128, NB, 16 q-slices of 256); wave holds 32 stationary k.
__global__ __launch_bounds__(256, 8) void lsum_kernel(const unsigned short* __restrict__ Qs,
                                                      const unsigned short* __restrict__ Ks,
                                                      float* __restrict__ l) {
    int tid = threadIdx.x;
    int w = tid >> 6, lane = tid & 63, quad = lane >> 4, m16 = lane & 15;
    int n = blockIdx.y;
    int kbase = blockIdx.x * 128 + w * 32;

    const unsigned short* Kp = Ks + (size_t)n * NSTRIDE + (kbase >> 4) * 1024 + lane * 8;
    short8 ka0 = *(const short8*)(Kp);
    short8 ka1 = *(const short8*)(Kp + 512);
    short8 kb0 = *(const short8*)(Kp + 1024);
    short8 kb1 = *(const short8*)(Kp + 1536);

    const unsigned short* Qp = Qs + (size_t)n * NSTRIDE + blockIdx.z * 16384 + lane * 8;

    float lA[4] = {0.f, 0.f, 0.f, 0.f};
    float lB[4] = {0.f, 0.f, 0.f, 0.f};
#pragma unroll 4
    for (int qc = 0; qc < 16; ++qc) {
        short8 qf0 = *(const short8*)(Qp);
        short8 qf1 = *(const short8*)(Qp + 512);
        f32x4 a = {0.f, 0.f, 0.f, 0.f}, b = {0.f, 0.f, 0.f, 0.f};
        a = __builtin_amdgcn_mfma_f32_16x16x32_bf16(ka0, qf0, a, 0, 0, 0);
        a = __builtin_amdgcn_mfma_f32_16x16x32_bf16(ka1, qf1, a, 0, 0, 0);
        b = __builtin_amdgcn_mfma_f32_16x16x32_bf16(kb0, qf0, b, 0, 0, 0);
        b = __builtin_amdgcn_mfma_f32_16x16x32_bf16(kb1, qf1, b, 0, 0, 0);
#pragma unroll
        for (int r = 0; r < 4; ++r) {
            lA[r] += fexp2(a[r]);
            lB[r] += fexp2(b[r]);
        }
        Qp += 1024;
    }
#pragma unroll
    for (int r = 0; r < 4; ++r)
        for (int d = 1; d < 16; d <<= 1) {
            lA[r] += __shfl_xor(lA[r], d);
            lB[r] += __shfl_xor(lB[r], d);
        }
    if (m16 == 0) {
        float* lp = l + n * HWN + kbase + quad * 4;
#pragma unroll
        for (int r = 0; r < 4; ++r) {
            atomicAdd(lp + r, lA[r]);
            atomicAdd(lp + 16 + r, lB[r]);
        }
    }
}

// ---------- prep: Vts = frag-major bf16(V[n][k][c] / l[n][k]), [c][k]-tiled ----------
__global__ __launch_bounds__(256) void prep_v(const float* __restrict__ V,
                                              const float* __restrict__ l,
                                              unsigned short* __restrict__ Vts) {
    __shared__ float rl[64];
    __shared__ float tile[64][65];
    int tid = threadIdx.x, n = blockIdx.y, kbase = blockIdx.x * 64;
    if (tid < 64) rl[tid] = 1.0f / l[n * HWN + kbase + tid];
    __syncthreads();
#pragma unroll
    for (int i = 0; i < 16; ++i) {
        int e = i * 256 + tid;
        int k = e >> 6, c = e & 63;
        tile[c][k] = V[((size_t)(n * HWN + kbase + k)) * CD + c] * rl[k];
    }
    __syncthreads();
#pragma unroll
    for (int i = 0; i < 2; ++i) {
        int s = i * 256 + tid;
        int c = s >> 3, kg = s & 7;
        int kl = kg * 8;
        int kgl = kbase + kl;
        short8 v;
#pragma unroll
        for (int j = 0; j < 8; ++j) v[j] = (short)f2bf(tile[c][kl + j]);
        size_t off = (size_t)n * NSTRIDE + (size_t)(kgl >> 5) * 2048 + (c >> 4) * 512 +
                     ((((kgl >> 3) & 3) * 16 + (c & 15)) * 8);
        *(short8*)(Vts + off) = v;
    }
}

// ---------- phase 2: out[q,c] += sum_k exp2(s'_kq) * V[k][c]/l[k] ----------
// grid (64 q-blocks of 64, NB, 4 k-slices). Wave w owns q-tile w*16; all 4
// waves share the same 1024-k slice (L1 dedup). S' orientation (A=K, B=Q):
// C-layout row=k=quad*4+r, col=q=m16 -> lane owns 4 consecutive k per tile,
// so P packs into bf16x2 pairs and stores with 2 ds_write_b64 per 16k.
// 64 k per iteration = two independent 32k sub-chains for ILP. No barriers.
__global__ __launch_bounds__(256, 4) void attn_kernel(const unsigned short* __restrict__ Qs,
                                                      const unsigned short* __restrict__ Ks,
                                                      const unsigned short* __restrict__ Vts,
                                                      float* __restrict__ out) {
    __shared__ short plds[4][16][72];  // [wave][q-row][k], pitch 72 shorts (144 B)
    int tid = threadIdx.x;
    int w = tid >> 6, lane = tid & 63, quad = lane >> 4, m16 = lane & 15;
    int n = blockIdx.y;
    int qbase = blockIdx.x * 64 + w * 16;

    // Q stationary (B-operand frags)
    const unsigned short* Qp = Qs + (size_t)n * NSTRIDE + (qbase >> 4) * 1024 + lane * 8;
    short8 qf0 = *(const short8*)(Qp);
    short8 qf1 = *(const short8*)(Qp + 512);

    // k-slice: 1024 k = 65536 elems in both Ks and Vts layouts
    size_t kofs = (size_t)blockIdx.z * 65536;
    const unsigned short* Kp = Ks + (size_t)n * NSTRIDE + kofs + lane * 8;
    const unsigned short* Vp = Vts + (size_t)n * NSTRIDE + kofs + lane * 8;

    f32x4 o[4];
#pragma unroll
    for (int ct = 0; ct < 4; ++ct) o[ct] = f32x4{0.f, 0.f, 0.f, 0.f};

    short* prow = &plds[w][m16][0];          // P row for q = qbase + m16
    const short* prd = &plds[w][m16][0];

    for (int it = 0; it < 16; ++it) {
        // ---- S' for k 0..31 of this 64k group (A=K, B=Q) ----
        short8 kf00 = *(const short8*)(Kp);
        short8 kf01 = *(const short8*)(Kp + 512);
        short8 kf10 = *(const short8*)(Kp + 1024);
        short8 kf11 = *(const short8*)(Kp + 1536);
        f32x4 sA = {0.f, 0.f, 0.f, 0.f}, sB = sA;
        sA = __builtin_amdgcn_mfma_f32_16x16x32_bf16(kf00, qf0, sA, 0, 0, 0);
        sA = __builtin_amdgcn_mfma_f32_16x16x32_bf16(kf01, qf1, sA, 0, 0, 0);
        sB = __builtin_amdgcn_mfma_f32_16x16x32_bf16(kf10, qf0, sB, 0, 0, 0);
        sB = __builtin_amdgcn_mfma_f32_16x16x32_bf16(kf11, qf1, sB, 0, 0, 0);
        // ---- S' for k 32..63 (independent chain) ----
        short8 kf20 = *(const short8*)(Kp + 2048);
        short8 kf21 = *(const short8*)(Kp + 2560);
        short8 kf30 = *(const short8*)(Kp + 3072);
        short8 kf31 = *(const short8*)(Kp + 3584);
        f32x4 sC = {0.f, 0.f, 0.f, 0.f}, sD = sC;
        sC = __builtin_amdgcn_mfma_f32_16x16x32_bf16(kf20, qf0, sC, 0, 0, 0);
        sC = __builtin_amdgcn_mfma_f32_16x16x32_bf16(kf21, qf1, sC, 0, 0, 0);
        sD = __builtin_amdgcn_mfma_f32_16x16x32_bf16(kf30, qf0, sD, 0, 0, 0);
        sD = __builtin_amdgcn_mfma_f32_16x16x32_bf16(kf31, qf1, sD, 0, 0, 0);

        // ---- P = exp2(S'): lane's 4 consecutive k per tile -> b64 stores ----
        uint2 pA, pB, pC, pD;
        pA.x = pk2(fexp2(sA[0]), fexp2(sA[1])); pA.y = pk2(fexp2(sA[2]), fexp2(sA[3]));
        pB.x = pk2(fexp2(sB[0]), fexp2(sB[1])); pB.y = pk2(fexp2(sB[2]), fexp2(sB[3]));
        pC.x = pk2(fexp2(sC[0]), fexp2(sC[1])); pC.y = pk2(fexp2(sC[2]), fexp2(sC[3]));
        pD.x = pk2(fexp2(sD[0]), fexp2(sD[1])); pD.y = pk2(fexp2(sD[2]), fexp2(sD[3]));
        *(uint2*)(prow + quad * 4)      = pA;   // k = quad*4+r
        *(uint2*)(prow + 16 + quad * 4) = pB;   // k = 16+quad*4+r
        *(uint2*)(prow + 32 + quad * 4) = pC;
        *(uint2*)(prow + 48 + quad * 4) = pD;

        // ---- A-frag reads (in-wave DS is in-order; no barrier) ----
        short8 pf0 = *(const short8*)(prd + quad * 8);        // k 0..31 chunk
        short8 pf1 = *(const short8*)(prd + 32 + quad * 8);   // k 32..63 chunk

        // ---- PV: o[ct] += P(A) x Vt(B), two 32k chunks ----
#pragma unroll
        for (int ct = 0; ct < 4; ++ct) {
            short8 vf0 = *(const short8*)(Vp + ct * 512);
            short8 vf1 = *(const short8*)(Vp + 2048 + ct * 512);
            o[ct] = __builtin_amdgcn_mfma_f32_16x16x32_bf16(pf0, vf0, o[ct], 0, 0, 0);
            o[ct] = __builtin_amdgcn_mfma_f32_16x16x32_bf16(pf1, vf1, o[ct], 0, 0, 0);
        }
        Kp += 4096;
        Vp += 4096;
    }

    // o[ct][r] = O_partial[q = quad*4+r][c = ct*16 + m16]; 4-way k-split -> atomics
    float* op = out + ((size_t)(n * HWN + qbase + quad * 4)) * CD + m16;
#pragma unroll
    for (int ct = 0; ct < 4; ++ct)
#pragma unroll
        for (int r = 0; r < 4; ++r)
            atomicAdd(op + r * CD + ct * 16, o[ct][r]);
}

extern "C" void kernel_launch(void* const* d_in, const int* in_sizes, int n_in,
                              void* d_out, int out_size, void* d_ws, size_t ws_size,
                              hipStream_t stream) {
    const float* Q = (const float*)d_in[0];
    const float* K = (const float*)d_in[1];
    const float* V = (const float*)d_in[2];
    float* out = (float*)d_out;

    char* ws = (char*)d_ws;
    unsigned short* Qs  = (unsigned short*)(ws);                   // 2 MB
    unsigned short* Ks  = (unsigned short*)(ws + (1u << 21));      // 2 MB
    unsigned short* Vts = (unsigned short*)(ws + (2u << 21));      // 2 MB
    float* l = (float*)(ws + (3u << 21));                          // 64 KB

    (void)hipMemsetAsync(out, 0, (size_t)NB * HWN * CD * sizeof(float), stream);
    (void)hipMemsetAsync(l, 0, (size_t)NB * HWN * sizeof(float), stream);

    cvt_qk<<<1024, 256, 0, stream>>>(Q, K, Qs, Ks);
    lsum_kernel<<<dim3(32, NB, 16), 256, 0, stream>>>(Qs, Ks, l);
    prep_v<<<dim3(64, NB), 256, 0, stream>>>(V, l, Vts);
    attn_kernel<<<dim3(64, NB, 4), 256, 0, stream>>>(Qs, Ks, Vts, out);
}

// Round 11
// 136.023 us; speedup vs baseline: 2.2995x; 1.0440x over previous
//
#include <hip/hip_runtime.h>

#define NB 4
#define HWN 4096
#define CD 64
#define NSTRIDE (HWN * CD)  // 262144 elems per batch in all swizzled buffers

typedef short short8 __attribute__((ext_vector_type(8), may_alias));
typedef float f32x4 __attribute__((ext_vector_type(4), may_alias));

__device__ constexpr float C1 = 0.18033688011112042f; // log2(e)/8 (folded into Qs)

__device__ __forceinline__ unsigned short f2bf(float f) {
    unsigned u = __builtin_bit_cast(unsigned, f);
    u = (u + 0x7FFFu + ((u >> 16) & 1u)) >> 16;  // RTN-even
    return (unsigned short)u;
}

__device__ __forceinline__ float fexp2(float x) {
#if __has_builtin(__builtin_amdgcn_exp2f)
    return __builtin_amdgcn_exp2f(x);
#else
    return exp2f(x);
#endif
}

// Frag-major swizzle for a row-major [R][64] matrix, 16-row tiles:
// elem(row, c) -> tile = row>>4, half = c>>5, lane l = ((c>>3)&3)*16 + (row&15),
// offset = tile*1024 + half*512 + l*8 + (c&7).
__device__ __forceinline__ size_t qk_swz(int row, int c) {
    return (size_t)(row >> 4) * 1024 + (c >> 5) * 512 +
           ((((c >> 3) & 3) * 16 + (row & 15)) * 8) + (c & 7);
}

// ---------- prep: Qs = bf16(C1*Q) swizzled, Ks = bf16(K) swizzled ----------
__global__ __launch_bounds__(256) void cvt_qk(const float* __restrict__ Q,
                                              const float* __restrict__ K,
                                              unsigned short* __restrict__ Qs,
                                              unsigned short* __restrict__ Ks) {
    int i = (blockIdx.x * 256 + threadIdx.x) * 4;
    int rg = i >> 6, c = i & 63;
    int n = rg >> 12, r = rg & 4095;
    float4 q = *(const float4*)(Q + i);
    float4 k = *(const float4*)(K + i);
    ushort4 qo, ko;
    qo.x = f2bf(q.x * C1); qo.y = f2bf(q.y * C1);
    qo.z = f2bf(q.z * C1); qo.w = f2bf(q.w * C1);
    ko.x = f2bf(k.x); ko.y = f2bf(k.y); ko.z = f2bf(k.z); ko.w = f2bf(k.w);
    size_t off = (size_t)n * NSTRIDE + qk_swz(r, c);
    *(ushort4*)(Qs + off) = qo;
    *(ushort4*)(Ks + off) = ko;
}

// ---------- phase 1: l[n,k] = sum_q exp2(dot(C1*Q[q], K[k])) ----------
// 1D grid 2048, XCD-swizzled: bid&7 -> (n, k-half) so each XCD's L2 holds
// K-slice (256 KB) + Qs[n] (512 KB). Wave holds 32 stationary k, streams Q.
__global__ __launch_bounds__(256, 8) void lsum_kernel(const unsigned short* __restrict__ Qs,
                                                      const unsigned short* __restrict__ Ks,
                                                      float* __restrict__ l) {
    int bid = blockIdx.x;
    int sel = bid & 7;            // XCD select (round-robin heuristic)
    int n = sel >> 1, kh = sel & 1;
    int r = bid >> 3;             // 0..255
    int kb = kh * 16 + (r & 15);  // 32 k-blocks of 128
    int z = r >> 4;               // 16 q-slices of 256

    int tid = threadIdx.x;
    int w = tid >> 6, lane = tid & 63, quad = lane >> 4, m16 = lane & 15;
    int kbase = kb * 128 + w * 32;

    const unsigned short* Kp = Ks + (size_t)n * NSTRIDE + (kbase >> 4) * 1024 + lane * 8;
    short8 ka0 = *(const short8*)(Kp);
    short8 ka1 = *(const short8*)(Kp + 512);
    short8 kb0 = *(const short8*)(Kp + 1024);
    short8 kb1 = *(const short8*)(Kp + 1536);

    const unsigned short* Qp = Qs + (size_t)n * NSTRIDE + z * 16384 + lane * 8;

    float lA[4] = {0.f, 0.f, 0.f, 0.f};
    float lB[4] = {0.f, 0.f, 0.f, 0.f};
#pragma unroll 4
    for (int qc = 0; qc < 16; ++qc) {
        short8 qf0 = *(const short8*)(Qp);
        short8 qf1 = *(const short8*)(Qp + 512);
        f32x4 a = {0.f, 0.f, 0.f, 0.f}, b = {0.f, 0.f, 0.f, 0.f};
        a = __builtin_amdgcn_mfma_f32_16x16x32_bf16(ka0, qf0, a, 0, 0, 0);
        a = __builtin_amdgcn_mfma_f32_16x16x32_bf16(ka1, qf1, a, 0, 0, 0);
        b = __builtin_amdgcn_mfma_f32_16x16x32_bf16(kb0, qf0, b, 0, 0, 0);
        b = __builtin_amdgcn_mfma_f32_16x16x32_bf16(kb1, qf1, b, 0, 0, 0);
#pragma unroll
        for (int rr = 0; rr < 4; ++rr) {
            lA[rr] += fexp2(a[rr]);
            lB[rr] += fexp2(b[rr]);
        }
        Qp += 1024;
    }
#pragma unroll
    for (int rr = 0; rr < 4; ++rr)
        for (int d = 1; d < 16; d <<= 1) {
            lA[rr] += __shfl_xor(lA[rr], d);
            lB[rr] += __shfl_xor(lB[rr], d);
        }
    if (m16 == 0) {
        float* lp = l + n * HWN + kbase + quad * 4;
#pragma unroll
        for (int rr = 0; rr < 4; ++rr) {
            atomicAdd(lp + rr, lA[rr]);
            atomicAdd(lp + 16 + rr, lB[rr]);
        }
    }
}

// ---------- prep: Vts = frag-major bf16(V[n][k][c] / l[n][k]), [c][k]-tiled ----------
__global__ __launch_bounds__(256) void prep_v(const float* __restrict__ V,
                                              const float* __restrict__ l,
                                              unsigned short* __restrict__ Vts) {
    __shared__ float rl[64];
    __shared__ float tile[64][65];
    int tid = threadIdx.x, n = blockIdx.y, kbase = blockIdx.x * 64;
    if (tid < 64) rl[tid] = 1.0f / l[n * HWN + kbase + tid];
    __syncthreads();
#pragma unroll
    for (int i = 0; i < 16; ++i) {
        int e = i * 256 + tid;
        int k = e >> 6, c = e & 63;
        tile[c][k] = V[((size_t)(n * HWN + kbase + k)) * CD + c] * rl[k];
    }
    __syncthreads();
#pragma unroll
    for (int i = 0; i < 2; ++i) {
        int s = i * 256 + tid;
        int c = s >> 3, kg = s & 7;
        int kl = kg * 8;
        int kgl = kbase + kl;
        short8 v;
#pragma unroll
        for (int j = 0; j < 8; ++j) v[j] = (short)f2bf(tile[c][kl + j]);
        size_t off = (size_t)n * NSTRIDE + (size_t)(kgl >> 5) * 2048 + (c >> 4) * 512 +
                     ((((kgl >> 3) & 3) * 16 + (c & 15)) * 8);
        *(short8*)(Vts + off) = v;
    }
}

// ---------- phase 2: out[q,c] += sum_k exp2(s_qk) * V[k][c]/l[k] ----------
// 1D grid 2048, XCD-swizzled: bid&7 -> (n, k-half) so each XCD's L2 holds
// Ks/Vts slices (512 KB) + Qs[n] (512 KB). R7's proven pipeline body: K/V
// register-prefetched 1 iter ahead, P via per-wave double-buffered LDS
// consumed one iteration later. Wave w owns q-tile w*16. Atomic epilogue.
__global__ __launch_bounds__(256, 4) void attn_kernel(const unsigned short* __restrict__ Qs,
                                                      const unsigned short* __restrict__ Ks,
                                                      const unsigned short* __restrict__ Vts,
                                                      float* __restrict__ out) {
    __shared__ short plds[4][2][16][40];  // [wave][buf][q-row][k], stride 40 bf16
    int bid = blockIdx.x;
    int sel = bid & 7;            // XCD select
    int n = sel >> 1, khalf = sel & 1;
    int r = bid >> 3;             // 0..255
    int qb = r & 63;              // 64 q-blocks of 64
    int kq = r >> 6;              // 0..3
    int kslice = khalf * 4 + kq;  // 8 k-slices of 512
    const int nit = 16;           // 512 k / 32 per iter

    int tid = threadIdx.x;
    int w = tid >> 6, lane = tid & 63, quad = lane >> 4, m16 = lane & 15;
    int qbase = qb * 64 + w * 16;

    const unsigned short* Qp = Qs + (size_t)n * NSTRIDE + (qbase >> 4) * 1024 + lane * 8;
    short8 qf0 = *(const short8*)(Qp);
    short8 qf1 = *(const short8*)(Qp + 512);

    size_t kofs = (size_t)kslice * 32768;  // 512 k x 64 elems
    const unsigned short* Kp = Ks + (size_t)n * NSTRIDE + kofs + lane * 8;
    const unsigned short* Vp = Vts + (size_t)n * NSTRIDE + kofs + lane * 8;

    f32x4 o[4];
#pragma unroll
    for (int ct = 0; ct < 4; ++ct) o[ct] = f32x4{0.f, 0.f, 0.f, 0.f};

    short* pw0 = &plds[w][0][0][0];
    short* pw1 = &plds[w][1][0][0];
    int wr_off = (quad * 4) * 40 + m16;   // P store base (C-layout row=q, col=k)
    int rd_off = m16 * 40 + quad * 8;     // A-frag read base

    short8 kc0, kc1, kc2, kc3, vp0, vp1, vp2, vp3;

    // ---- prologue: it = 0 ----
    kc0 = *(const short8*)(Kp);
    kc1 = *(const short8*)(Kp + 512);
    kc2 = *(const short8*)(Kp + 1024);
    kc3 = *(const short8*)(Kp + 1536);
    Kp += 2048;
    vp0 = *(const short8*)(Vp);
    vp1 = *(const short8*)(Vp + 512);
    vp2 = *(const short8*)(Vp + 1024);
    vp3 = *(const short8*)(Vp + 1536);
    Vp += 2048;
    {
        f32x4 s0 = {0.f, 0.f, 0.f, 0.f}, s1 = {0.f, 0.f, 0.f, 0.f};
        s0 = __builtin_amdgcn_mfma_f32_16x16x32_bf16(qf0, kc0, s0, 0, 0, 0);
        s0 = __builtin_amdgcn_mfma_f32_16x16x32_bf16(qf1, kc1, s0, 0, 0, 0);
        s1 = __builtin_amdgcn_mfma_f32_16x16x32_bf16(qf0, kc2, s1, 0, 0, 0);
        s1 = __builtin_amdgcn_mfma_f32_16x16x32_bf16(qf1, kc3, s1, 0, 0, 0);
        short* prow = pw0 + wr_off;
#pragma unroll
        for (int rr = 0; rr < 4; ++rr) {
            prow[rr * 40]      = (short)f2bf(fexp2(s0[rr]));
            prow[rr * 40 + 16] = (short)f2bf(fexp2(s1[rr]));
        }
    }
    // K(1) for the first loop body
    kc0 = *(const short8*)(Kp);
    kc1 = *(const short8*)(Kp + 512);
    kc2 = *(const short8*)(Kp + 1024);
    kc3 = *(const short8*)(Kp + 1536);
    Kp += 2048;

    // ---- pipelined body: it = 1 .. nit-1 ----
#pragma unroll 2
    for (int it = 1; it < nit; ++it) {
        // prefetch K(it+1) (overread at it=nit-1: lands in-ws, unused)
        short8 kn0 = *(const short8*)(Kp);
        short8 kn1 = *(const short8*)(Kp + 512);
        short8 kn2 = *(const short8*)(Kp + 1024);
        short8 kn3 = *(const short8*)(Kp + 1536);
        Kp += 2048;
        // V(it): consumed next iteration
        short8 vn0 = *(const short8*)(Vp);
        short8 vn1 = *(const short8*)(Vp + 512);
        short8 vn2 = *(const short8*)(Vp + 1024);
        short8 vn3 = *(const short8*)(Vp + 1536);
        Vp += 2048;

        // S(it) from kc = K(it), loaded one iteration ago
        f32x4 s0 = {0.f, 0.f, 0.f, 0.f}, s1 = {0.f, 0.f, 0.f, 0.f};
        s0 = __builtin_amdgcn_mfma_f32_16x16x32_bf16(qf0, kc0, s0, 0, 0, 0);
        s0 = __builtin_amdgcn_mfma_f32_16x16x32_bf16(qf1, kc1, s0, 0, 0, 0);
        s1 = __builtin_amdgcn_mfma_f32_16x16x32_bf16(qf0, kc2, s1, 0, 0, 0);
        s1 = __builtin_amdgcn_mfma_f32_16x16x32_bf16(qf1, kc3, s1, 0, 0, 0);

        // P(it-1): written one iteration ago -> DS latency already paid
        short* pr = ((it & 1) ? pw0 : pw1) + rd_off;
        short8 pf = *(const short8*)pr;
#pragma unroll
        for (int ct = 0; ct < 4; ++ct) {
            short8 vf;
            switch (ct) { case 0: vf = vp0; break; case 1: vf = vp1; break;
                          case 2: vf = vp2; break; default: vf = vp3; }
            o[ct] = __builtin_amdgcn_mfma_f32_16x16x32_bf16(pf, vf, o[ct], 0, 0, 0);
        }

        // P(it) -> other LDS buffer
        short* prow = ((it & 1) ? pw1 : pw0) + wr_off;
#pragma unroll
        for (int rr = 0; rr < 4; ++rr) {
            prow[rr * 40]      = (short)f2bf(fexp2(s0[rr]));
            prow[rr * 40 + 16] = (short)f2bf(fexp2(s1[rr]));
        }

        kc0 = kn0; kc1 = kn1; kc2 = kn2; kc3 = kn3;
        vp0 = vn0; vp1 = vn1; vp2 = vn2; vp3 = vn3;
    }

    // ---- epilogue: PV for it = nit-1 ----
    {
        short* pr = ((nit & 1) ? pw0 : pw1) + rd_off;
        short8 pf = *(const short8*)pr;
        o[0] = __builtin_amdgcn_mfma_f32_16x16x32_bf16(pf, vp0, o[0], 0, 0, 0);
        o[1] = __builtin_amdgcn_mfma_f32_16x16x32_bf16(pf, vp1, o[1], 0, 0, 0);
        o[2] = __builtin_amdgcn_mfma_f32_16x16x32_bf16(pf, vp2, o[2], 0, 0, 0);
        o[3] = __builtin_amdgcn_mfma_f32_16x16x32_bf16(pf, vp3, o[3], 0, 0, 0);
    }

    // o[ct][r] = O[q = quad*4+r][c = ct*16 + m16]; 8-way k-split -> atomics
    float* op = out + ((size_t)(n * HWN + qbase + quad * 4)) * CD + m16;
#pragma unroll
    for (int ct = 0; ct < 4; ++ct)
#pragma unroll
        for (int rr = 0; rr < 4; ++rr)
            atomicAdd(op + rr * CD + ct * 16, o[ct][rr]);
}

extern "C" void kernel_launch(void* const* d_in, const int* in_sizes, int n_in,
                              void* d_out, int out_size, void* d_ws, size_t ws_size,
                              hipStream_t stream) {
    const float* Q = (const float*)d_in[0];
    const float* K = (const float*)d_in[1];
    const float* V = (const float*)d_in[2];
    float* out = (float*)d_out;

    char* ws = (char*)d_ws;
    unsigned short* Qs  = (unsigned short*)(ws);                   // 2 MB
    unsigned short* Ks  = (unsigned short*)(ws + (1u << 21));      // 2 MB
    unsigned short* Vts = (unsigned short*)(ws + (2u << 21));      // 2 MB
    float* l = (float*)(ws + (3u << 21));                          // 64 KB

    (void)hipMemsetAsync(out, 0, (size_t)NB * HWN * CD * sizeof(float), stream);
    (void)hipMemsetAsync(l, 0, (size_t)NB * HWN * sizeof(float), stream);

    cvt_qk<<<1024, 256, 0, stream>>>(Q, K, Qs, Ks);
    lsum_kernel<<<2048, 256, 0, stream>>>(Qs, Ks, l);
    prep_v<<<dim3(64, NB), 256, 0, stream>>>(V, l, Vts);
    attn_kernel<<<2048, 256, 0, stream>>>(Qs, Ks, Vts, out);
}

// Round 12
// 119.645 us; speedup vs baseline: 2.6143x; 1.1369x over previous
//
#include <hip/hip_runtime.h>

#define NB 4
#define HWN 4096
#define CD 64
#define NSTRIDE (HWN * CD)  // 262144 elems per batch in all swizzled buffers

typedef short short8 __attribute__((ext_vector_type(8), may_alias));
typedef float f32x4 __attribute__((ext_vector_type(4), may_alias));

__device__ constexpr float C1 = 0.18033688011112042f; // log2(e)/8 (folded into Qs)

__device__ __forceinline__ unsigned short f2bf(float f) {
    unsigned u = __builtin_bit_cast(unsigned, f);
    u = (u + 0x7FFFu + ((u >> 16) & 1u)) >> 16;  // RTN-even
    return (unsigned short)u;
}

__device__ __forceinline__ float fexp2(float x) {
#if __has_builtin(__builtin_amdgcn_exp2f)
    return __builtin_amdgcn_exp2f(x);
#else
    return exp2f(x);
#endif
}

// Frag-major swizzle for a row-major [R][64] matrix, 16-row tiles:
// elem(row, c) -> tile = row>>4, half = c>>5, lane l = ((c>>3)&3)*16 + (row&15),
// offset = tile*1024 + half*512 + l*8 + (c&7).
__device__ __forceinline__ size_t qk_swz(int row, int c) {
    return (size_t)(row >> 4) * 1024 + (c >> 5) * 512 +
           ((((c >> 3) & 3) * 16 + (row & 15)) * 8) + (c & 7);
}

// ---------- prep: Qs = bf16(C1*Q) swizzled, Ks = bf16(K) swizzled ----------
__global__ __launch_bounds__(256) void cvt_qk(const float* __restrict__ Q,
                                              const float* __restrict__ K,
                                              unsigned short* __restrict__ Qs,
                                              unsigned short* __restrict__ Ks) {
    int i = (blockIdx.x * 256 + threadIdx.x) * 4;
    int rg = i >> 6, c = i & 63;
    int n = rg >> 12, r = rg & 4095;
    float4 q = *(const float4*)(Q + i);
    float4 k = *(const float4*)(K + i);
    ushort4 qo, ko;
    qo.x = f2bf(q.x * C1); qo.y = f2bf(q.y * C1);
    qo.z = f2bf(q.z * C1); qo.w = f2bf(q.w * C1);
    ko.x = f2bf(k.x); ko.y = f2bf(k.y); ko.z = f2bf(k.z); ko.w = f2bf(k.w);
    size_t off = (size_t)n * NSTRIDE + qk_swz(r, c);
    *(ushort4*)(Qs + off) = qo;
    *(ushort4*)(Ks + off) = ko;
}

// ---------- phase 1: l[n,k] = sum_q exp2(dot(C1*Q[q], K[k])) ----------
// grid (32 k-blocks of 128, NB, 16 q-slices of 256); wave holds 32 stationary k.
// waves_per_eu(4,8): 128-VGPR scheduling budget so the Q-prefetch stays live.
__global__ __attribute__((amdgpu_flat_work_group_size(256, 256), amdgpu_waves_per_eu(4, 8)))
void lsum_kernel(const unsigned short* __restrict__ Qs,
                 const unsigned short* __restrict__ Ks,
                 float* __restrict__ l) {
    int tid = threadIdx.x;
    int w = tid >> 6, lane = tid & 63, quad = lane >> 4, m16 = lane & 15;
    int n = blockIdx.y;
    int kbase = blockIdx.x * 128 + w * 32;

    const unsigned short* Kp = Ks + (size_t)n * NSTRIDE + (kbase >> 4) * 1024 + lane * 8;
    short8 ka0 = *(const short8*)(Kp);
    short8 ka1 = *(const short8*)(Kp + 512);
    short8 kb0 = *(const short8*)(Kp + 1024);
    short8 kb1 = *(const short8*)(Kp + 1536);

    const unsigned short* Qp = Qs + (size_t)n * NSTRIDE + blockIdx.z * 16384 + lane * 8;

    short8 qc0 = *(const short8*)(Qp);
    short8 qc1 = *(const short8*)(Qp + 512);
    Qp += 1024;

    float lA[4] = {0.f, 0.f, 0.f, 0.f};
    float lB[4] = {0.f, 0.f, 0.f, 0.f};
#pragma unroll 2
    for (int qc = 0; qc < 16; ++qc) {
        short8 qn0 = *(const short8*)(Qp);        // prefetch next (overread at end: in-ws)
        short8 qn1 = *(const short8*)(Qp + 512);
        f32x4 a = {0.f, 0.f, 0.f, 0.f}, b = {0.f, 0.f, 0.f, 0.f};
        a = __builtin_amdgcn_mfma_f32_16x16x32_bf16(ka0, qc0, a, 0, 0, 0);
        a = __builtin_amdgcn_mfma_f32_16x16x32_bf16(ka1, qc1, a, 0, 0, 0);
        b = __builtin_amdgcn_mfma_f32_16x16x32_bf16(kb0, qc0, b, 0, 0, 0);
        b = __builtin_amdgcn_mfma_f32_16x16x32_bf16(kb1, qc1, b, 0, 0, 0);
#pragma unroll
        for (int r = 0; r < 4; ++r) {
            lA[r] += fexp2(a[r]);
            lB[r] += fexp2(b[r]);
        }
        qc0 = qn0; qc1 = qn1;
        Qp += 1024;
    }
#pragma unroll
    for (int r = 0; r < 4; ++r)
        for (int d = 1; d < 16; d <<= 1) {
            lA[r] += __shfl_xor(lA[r], d);
            lB[r] += __shfl_xor(lB[r], d);
        }
    if (m16 == 0) {
        float* lp = l + n * HWN + kbase + quad * 4;
#pragma unroll
        for (int r = 0; r < 4; ++r) {
            atomicAdd(lp + r, lA[r]);
            atomicAdd(lp + 16 + r, lB[r]);
        }
    }
}

// ---------- prep: Vts = frag-major bf16(V[n][k][c] / l[n][k]), [c][k]-tiled ----------
__global__ __launch_bounds__(256) void prep_v(const float* __restrict__ V,
                                              const float* __restrict__ l,
                                              unsigned short* __restrict__ Vts) {
    __shared__ float rl[64];
    __shared__ float tile[64][65];
    int tid = threadIdx.x, n = blockIdx.y, kbase = blockIdx.x * 64;
    if (tid < 64) rl[tid] = 1.0f / l[n * HWN + kbase + tid];
    __syncthreads();
#pragma unroll
    for (int i = 0; i < 16; ++i) {
        int e = i * 256 + tid;
        int k = e >> 6, c = e & 63;
        tile[c][k] = V[((size_t)(n * HWN + kbase + k)) * CD + c] * rl[k];
    }
    __syncthreads();
#pragma unroll
    for (int i = 0; i < 2; ++i) {
        int s = i * 256 + tid;
        int c = s >> 3, kg = s & 7;
        int kl = kg * 8;
        int kgl = kbase + kl;
        short8 v;
#pragma unroll
        for (int j = 0; j < 8; ++j) v[j] = (short)f2bf(tile[c][kl + j]);
        size_t off = (size_t)n * NSTRIDE + (size_t)(kgl >> 5) * 2048 + (c >> 4) * 512 +
                     ((((kgl >> 3) & 3) * 16 + (c & 15)) * 8);
        *(short8*)(Vts + off) = v;
    }
}

// ---------- phase 2: out[q,c] = sum_k exp2(s_qk) * V[k][c]/l[k] ----------
// grid (64 q-blocks of 64, NB, ns k-slices). Wave w owns q-tile w*16.
// R7 pipeline: K/V register-prefetched 1 iter ahead; P via per-wave dbuf LDS
// consumed one iteration later. waves_per_eu(2,4): 256-VGPR scheduling budget
// so the K/V prefetch + V-carry actually stay in registers (R7 had them sunk).
__global__ __attribute__((amdgpu_flat_work_group_size(256, 256), amdgpu_waves_per_eu(2, 4)))
void attn_kernel(const unsigned short* __restrict__ Qs,
                 const unsigned short* __restrict__ Ks,
                 const unsigned short* __restrict__ Vts,
                 float* __restrict__ partial,
                 int nit) {
    __shared__ short plds[4][2][16][40];  // [wave][buf][q-row][k], stride 40 bf16
    int tid = threadIdx.x;
    int w = tid >> 6, lane = tid & 63, quad = lane >> 4, m16 = lane & 15;
    int n = blockIdx.y;
    int qbase = blockIdx.x * 64 + w * 16;

    const unsigned short* Qp = Qs + (size_t)n * NSTRIDE + (qbase >> 4) * 1024 + lane * 8;
    short8 qf0 = *(const short8*)(Qp);
    short8 qf1 = *(const short8*)(Qp + 512);

    size_t kofs = (size_t)blockIdx.z * (size_t)nit * 2048;
    const unsigned short* Kp = Ks + (size_t)n * NSTRIDE + kofs + lane * 8;
    const unsigned short* Vp = Vts + (size_t)n * NSTRIDE + kofs + lane * 8;

    f32x4 o[4];
#pragma unroll
    for (int ct = 0; ct < 4; ++ct) o[ct] = f32x4{0.f, 0.f, 0.f, 0.f};

    short* pw0 = &plds[w][0][0][0];
    short* pw1 = &plds[w][1][0][0];
    int wr_off = (quad * 4) * 40 + m16;   // P store base (C-layout row=q, col=k)
    int rd_off = m16 * 40 + quad * 8;     // A-frag read base

    short8 kc0, kc1, kc2, kc3, vp0, vp1, vp2, vp3;

    // ---- prologue: it = 0 ----
    kc0 = *(const short8*)(Kp);
    kc1 = *(const short8*)(Kp + 512);
    kc2 = *(const short8*)(Kp + 1024);
    kc3 = *(const short8*)(Kp + 1536);
    Kp += 2048;
    vp0 = *(const short8*)(Vp);
    vp1 = *(const short8*)(Vp + 512);
    vp2 = *(const short8*)(Vp + 1024);
    vp3 = *(const short8*)(Vp + 1536);
    Vp += 2048;
    {
        f32x4 s0 = {0.f, 0.f, 0.f, 0.f}, s1 = {0.f, 0.f, 0.f, 0.f};
        s0 = __builtin_amdgcn_mfma_f32_16x16x32_bf16(qf0, kc0, s0, 0, 0, 0);
        s0 = __builtin_amdgcn_mfma_f32_16x16x32_bf16(qf1, kc1, s0, 0, 0, 0);
        s1 = __builtin_amdgcn_mfma_f32_16x16x32_bf16(qf0, kc2, s1, 0, 0, 0);
        s1 = __builtin_amdgcn_mfma_f32_16x16x32_bf16(qf1, kc3, s1, 0, 0, 0);
        short* prow = pw0 + wr_off;
#pragma unroll
        for (int rr = 0; rr < 4; ++rr) {
            prow[rr * 40]      = (short)f2bf(fexp2(s0[rr]));
            prow[rr * 40 + 16] = (short)f2bf(fexp2(s1[rr]));
        }
    }
    // K(1) for the first loop body
    kc0 = *(const short8*)(Kp);
    kc1 = *(const short8*)(Kp + 512);
    kc2 = *(const short8*)(Kp + 1024);
    kc3 = *(const short8*)(Kp + 1536);
    Kp += 2048;

    // ---- pipelined body: it = 1 .. nit-1 ----
#pragma unroll 2
    for (int it = 1; it < nit; ++it) {
        // prefetch K(it+1) (overread at it=nit-1: lands in-ws, unused)
        short8 kn0 = *(const short8*)(Kp);
        short8 kn1 = *(const short8*)(Kp + 512);
        short8 kn2 = *(const short8*)(Kp + 1024);
        short8 kn3 = *(const short8*)(Kp + 1536);
        Kp += 2048;
        // V(it): consumed next iteration
        short8 vn0 = *(const short8*)(Vp);
        short8 vn1 = *(const short8*)(Vp + 512);
        short8 vn2 = *(const short8*)(Vp + 1024);
        short8 vn3 = *(const short8*)(Vp + 1536);
        Vp += 2048;

        // S(it) from kc = K(it), loaded one iteration ago
        f32x4 s0 = {0.f, 0.f, 0.f, 0.f}, s1 = {0.f, 0.f, 0.f, 0.f};
        s0 = __builtin_amdgcn_mfma_f32_16x16x32_bf16(qf0, kc0, s0, 0, 0, 0);
        s0 = __builtin_amdgcn_mfma_f32_16x16x32_bf16(qf1, kc1, s0, 0, 0, 0);
        s1 = __builtin_amdgcn_mfma_f32_16x16x32_bf16(qf0, kc2, s1, 0, 0, 0);
        s1 = __builtin_amdgcn_mfma_f32_16x16x32_bf16(qf1, kc3, s1, 0, 0, 0);

        // P(it-1): written one iteration ago -> DS latency already paid
        short* pr = ((it & 1) ? pw0 : pw1) + rd_off;
        short8 pf = *(const short8*)pr;
#pragma unroll
        for (int ct = 0; ct < 4; ++ct) {
            short8 vf;
            switch (ct) { case 0: vf = vp0; break; case 1: vf = vp1; break;
                          case 2: vf = vp2; break; default: vf = vp3; }
            o[ct] = __builtin_amdgcn_mfma_f32_16x16x32_bf16(pf, vf, o[ct], 0, 0, 0);
        }

        // P(it) -> other LDS buffer
        short* prow = ((it & 1) ? pw1 : pw0) + wr_off;
#pragma unroll
        for (int rr = 0; rr < 4; ++rr) {
            prow[rr * 40]      = (short)f2bf(fexp2(s0[rr]));
            prow[rr * 40 + 16] = (short)f2bf(fexp2(s1[rr]));
        }

        kc0 = kn0; kc1 = kn1; kc2 = kn2; kc3 = kn3;
        vp0 = vn0; vp1 = vn1; vp2 = vn2; vp3 = vn3;
    }

    // ---- epilogue: PV for it = nit-1 ----
    {
        short* pr = ((nit & 1) ? pw0 : pw1) + rd_off;
        short8 pf = *(const short8*)pr;
        o[0] = __builtin_amdgcn_mfma_f32_16x16x32_bf16(pf, vp0, o[0], 0, 0, 0);
        o[1] = __builtin_amdgcn_mfma_f32_16x16x32_bf16(pf, vp1, o[1], 0, 0, 0);
        o[2] = __builtin_amdgcn_mfma_f32_16x16x32_bf16(pf, vp2, o[2], 0, 0, 0);
        o[3] = __builtin_amdgcn_mfma_f32_16x16x32_bf16(pf, vp3, o[3], 0, 0, 0);
    }

    // o[ct][r] = O_partial[q = quad*4+r][c = ct*16 + m16]; plain stores
    float* pp = partial + (size_t)blockIdx.z * (NB * HWN * CD) +
                ((size_t)(n * HWN + qbase + quad * 4)) * CD + m16;
#pragma unroll
    for (int ct = 0; ct < 4; ++ct)
#pragma unroll
        for (int rr = 0; rr < 4; ++rr)
            pp[rr * CD + ct * 16] = o[ct][rr];
}

// ---------- final: out = sum of ns partial slices ----------
__global__ __launch_bounds__(256) void reduce_out(const float* __restrict__ p,
                                                  float* __restrict__ out, int ns) {
    int i = (blockIdx.x * 256 + threadIdx.x) * 4;
    f32x4 a = *(const f32x4*)(p + i);
    for (int s = 1; s < ns; ++s)
        a = a + *(const f32x4*)(p + (size_t)s * (NB * HWN * CD) + i);
    *(f32x4*)(out + i) = a;
}

extern "C" void kernel_launch(void* const* d_in, const int* in_sizes, int n_in,
                              void* d_out, int out_size, void* d_ws, size_t ws_size,
                              hipStream_t stream) {
    const float* Q = (const float*)d_in[0];
    const float* K = (const float*)d_in[1];
    const float* V = (const float*)d_in[2];
    float* out = (float*)d_out;

    char* ws = (char*)d_ws;
    unsigned short* Qs  = (unsigned short*)(ws);                   // 2 MB
    unsigned short* Ks  = (unsigned short*)(ws + (1u << 21));      // 2 MB
    unsigned short* Vts = (unsigned short*)(ws + (2u << 21));      // 2 MB
    float* l       = (float*)(ws + (3u << 21));                    // 64 KB
    float* partial = (float*)(ws + (4u << 21));                    // ns * 4 MB

    size_t base = (size_t)(4u << 21);
    size_t slice = (size_t)NB * HWN * CD * sizeof(float);
    int ns = (ws_size >= base + 4 * slice) ? 4 : 2;
    int nit = HWN / ns / 32;  // 32-k steps per wave: ns=4 -> 32, ns=2 -> 64

    (void)hipMemsetAsync(l, 0, (size_t)NB * HWN * sizeof(float), stream);

    cvt_qk<<<1024, 256, 0, stream>>>(Q, K, Qs, Ks);
    lsum_kernel<<<dim3(32, NB, 16), 256, 0, stream>>>(Qs, Ks, l);
    prep_v<<<dim3(64, NB), 256, 0, stream>>>(V, l, Vts);
    attn_kernel<<<dim3(64, NB, ns), 256, 0, stream>>>(Qs, Ks, Vts, partial, nit);
    reduce_out<<<1024, 256, 0, stream>>>(partial, out, ns);
}

// Round 13
// 115.028 us; speedup vs baseline: 2.7192x; 1.0401x over previous
//
#include <hip/hip_runtime.h>

#define NB 4
#define HWN 4096
#define CD 64
#define NSTRIDE (HWN * CD)  // 262144 elems per batch in all swizzled buffers

typedef short short8 __attribute__((ext_vector_type(8), may_alias));
typedef float f32x4 __attribute__((ext_vector_type(4), may_alias));

__device__ constexpr float C1 = 0.18033688011112042f; // log2(e)/8 (folded into Qs)

__device__ __forceinline__ unsigned short f2bf(float f) {
    unsigned u = __builtin_bit_cast(unsigned, f);
    u = (u + 0x7FFFu + ((u >> 16) & 1u)) >> 16;  // RTN-even
    return (unsigned short)u;
}

__device__ __forceinline__ float fexp2(float x) {
#if __has_builtin(__builtin_amdgcn_exp2f)
    return __builtin_amdgcn_exp2f(x);
#else
    return exp2f(x);
#endif
}

// Frag-major swizzle for a row-major [R][64] matrix, 16-row tiles:
// elem(row, c) -> tile = row>>4, half = c>>5, lane l = ((c>>3)&3)*16 + (row&15),
// offset = tile*1024 + half*512 + l*8 + (c&7).
__device__ __forceinline__ size_t qk_swz(int row, int c) {
    return (size_t)(row >> 4) * 1024 + (c >> 5) * 512 +
           ((((c >> 3) & 3) * 16 + (row & 15)) * 8) + (c & 7);
}

// ---------- prep: Qs = bf16(C1*Q) swizzled, Ks = bf16(K) swizzled ----------
__global__ __launch_bounds__(256) void cvt_qk(const float* __restrict__ Q,
                                              const float* __restrict__ K,
                                              unsigned short* __restrict__ Qs,
                                              unsigned short* __restrict__ Ks) {
    int i = (blockIdx.x * 256 + threadIdx.x) * 4;
    int rg = i >> 6, c = i & 63;
    int n = rg >> 12, r = rg & 4095;
    float4 q = *(const float4*)(Q + i);
    float4 k = *(const float4*)(K + i);
    ushort4 qo, ko;
    qo.x = f2bf(q.x * C1); qo.y = f2bf(q.y * C1);
    qo.z = f2bf(q.z * C1); qo.w = f2bf(q.w * C1);
    ko.x = f2bf(k.x); ko.y = f2bf(k.y); ko.z = f2bf(k.z); ko.w = f2bf(k.w);
    size_t off = (size_t)n * NSTRIDE + qk_swz(r, c);
    *(ushort4*)(Qs + off) = qo;
    *(ushort4*)(Ks + off) = ko;
}

// ---------- phase 1: l[n,k] = sum_q exp2(dot(C1*Q[q], K[k])) ----------
// Wave holds 64 stationary k (4 A-frag pairs); Q stream register-prefetched,
// shared by all 4 stationary tiles -> 2x MFMA/exp per Q-load vs R12.
// grid (16 k-blocks of 256, NB, 16 q-slices of 256).
__global__ __attribute__((amdgpu_flat_work_group_size(256, 256), amdgpu_waves_per_eu(2, 4)))
void lsum_kernel(const unsigned short* __restrict__ Qs,
                 const unsigned short* __restrict__ Ks,
                 float* __restrict__ l) {
    int tid = threadIdx.x;
    int w = tid >> 6, lane = tid & 63, quad = lane >> 4, m16 = lane & 15;
    int n = blockIdx.y;
    int kbase = blockIdx.x * 256 + w * 64;

    const unsigned short* Kp = Ks + (size_t)n * NSTRIDE + (kbase >> 4) * 1024 + lane * 8;
    short8 ka0 = *(const short8*)(Kp);
    short8 ka1 = *(const short8*)(Kp + 512);
    short8 kb0 = *(const short8*)(Kp + 1024);
    short8 kb1 = *(const short8*)(Kp + 1536);
    short8 kc0 = *(const short8*)(Kp + 2048);
    short8 kc1 = *(const short8*)(Kp + 2560);
    short8 kd0 = *(const short8*)(Kp + 3072);
    short8 kd1 = *(const short8*)(Kp + 3584);

    const unsigned short* Qp = Qs + (size_t)n * NSTRIDE + blockIdx.z * 16384 + lane * 8;

    short8 qc0 = *(const short8*)(Qp);
    short8 qc1 = *(const short8*)(Qp + 512);
    Qp += 1024;

    float lA[4] = {0.f, 0.f, 0.f, 0.f};
    float lB[4] = {0.f, 0.f, 0.f, 0.f};
    float lC[4] = {0.f, 0.f, 0.f, 0.f};
    float lD[4] = {0.f, 0.f, 0.f, 0.f};
#pragma unroll 2
    for (int qc = 0; qc < 16; ++qc) {
        short8 qn0 = *(const short8*)(Qp);        // prefetch next (overread at end: in-ws)
        short8 qn1 = *(const short8*)(Qp + 512);
        f32x4 a = {0.f, 0.f, 0.f, 0.f}, b = a, c = a, d = a;
        a = __builtin_amdgcn_mfma_f32_16x16x32_bf16(ka0, qc0, a, 0, 0, 0);
        a = __builtin_amdgcn_mfma_f32_16x16x32_bf16(ka1, qc1, a, 0, 0, 0);
        b = __builtin_amdgcn_mfma_f32_16x16x32_bf16(kb0, qc0, b, 0, 0, 0);
        b = __builtin_amdgcn_mfma_f32_16x16x32_bf16(kb1, qc1, b, 0, 0, 0);
        c = __builtin_amdgcn_mfma_f32_16x16x32_bf16(kc0, qc0, c, 0, 0, 0);
        c = __builtin_amdgcn_mfma_f32_16x16x32_bf16(kc1, qc1, c, 0, 0, 0);
        d = __builtin_amdgcn_mfma_f32_16x16x32_bf16(kd0, qc0, d, 0, 0, 0);
        d = __builtin_amdgcn_mfma_f32_16x16x32_bf16(kd1, qc1, d, 0, 0, 0);
#pragma unroll
        for (int r = 0; r < 4; ++r) {
            lA[r] += fexp2(a[r]);
            lB[r] += fexp2(b[r]);
            lC[r] += fexp2(c[r]);
            lD[r] += fexp2(d[r]);
        }
        qc0 = qn0; qc1 = qn1;
        Qp += 1024;
    }
#pragma unroll
    for (int r = 0; r < 4; ++r)
        for (int d1 = 1; d1 < 16; d1 <<= 1) {
            lA[r] += __shfl_xor(lA[r], d1);
            lB[r] += __shfl_xor(lB[r], d1);
            lC[r] += __shfl_xor(lC[r], d1);
            lD[r] += __shfl_xor(lD[r], d1);
        }
    if (m16 == 0) {
        float* lp = l + n * HWN + kbase + quad * 4;
#pragma unroll
        for (int r = 0; r < 4; ++r) {
            atomicAdd(lp + r, lA[r]);
            atomicAdd(lp + 16 + r, lB[r]);
            atomicAdd(lp + 32 + r, lC[r]);
            atomicAdd(lp + 48 + r, lD[r]);
        }
    }
}

// ---------- prep: Vts = frag-major bf16(V[n][k][c] / l[n][k]), [c][k]-tiled ----------
__global__ __launch_bounds__(256) void prep_v(const float* __restrict__ V,
                                              const float* __restrict__ l,
                                              unsigned short* __restrict__ Vts) {
    __shared__ float rl[64];
    __shared__ float tile[64][65];
    int tid = threadIdx.x, n = blockIdx.y, kbase = blockIdx.x * 64;
    if (tid < 64) rl[tid] = 1.0f / l[n * HWN + kbase + tid];
    __syncthreads();
#pragma unroll
    for (int i = 0; i < 16; ++i) {
        int e = i * 256 + tid;
        int k = e >> 6, c = e & 63;
        tile[c][k] = V[((size_t)(n * HWN + kbase + k)) * CD + c] * rl[k];
    }
    __syncthreads();
#pragma unroll
    for (int i = 0; i < 2; ++i) {
        int s = i * 256 + tid;
        int c = s >> 3, kg = s & 7;
        int kl = kg * 8;
        int kgl = kbase + kl;
        short8 v;
#pragma unroll
        for (int j = 0; j < 8; ++j) v[j] = (short)f2bf(tile[c][kl + j]);
        size_t off = (size_t)n * NSTRIDE + (size_t)(kgl >> 5) * 2048 + (c >> 4) * 512 +
                     ((((kgl >> 3) & 3) * 16 + (c & 15)) * 8);
        *(short8*)(Vts + off) = v;
    }
}

// ---------- phase 2: out[q,c] = sum_k exp2(s_qk) * V[k][c]/l[k] ----------
// grid (32 q-blocks of 128, NB, 8 k-slices). Wave owns TWO 16-q tiles
// (qbase, qbase+64) sharing each K/V load -> 2x MFMA/exp per load vs R12.
// R7 pipeline: K/V register-prefetched 1 iter ahead; P via per-wave dbuf LDS
// consumed one iteration later. waves_per_eu(2,4).
__global__ __attribute__((amdgpu_flat_work_group_size(256, 256), amdgpu_waves_per_eu(2, 4)))
void attn_kernel(const unsigned short* __restrict__ Qs,
                 const unsigned short* __restrict__ Ks,
                 const unsigned short* __restrict__ Vts,
                 float* __restrict__ partial,
                 int nit) {
    __shared__ short plds[4][2][2][16][40];  // [wave][buf][qtile][row][col]
    int tid = threadIdx.x;
    int w = tid >> 6, lane = tid & 63, quad = lane >> 4, m16 = lane & 15;
    int n = blockIdx.y;
    int qbase = blockIdx.x * 128 + w * 16;   // second tile at +64

    const unsigned short* Qp = Qs + (size_t)n * NSTRIDE + (qbase >> 4) * 1024 + lane * 8;
    short8 qf0 = *(const short8*)(Qp);
    short8 qf1 = *(const short8*)(Qp + 512);
    short8 qg0 = *(const short8*)(Qp + 4096);        // +64 q rows
    short8 qg1 = *(const short8*)(Qp + 4096 + 512);

    size_t kofs = (size_t)blockIdx.z * (size_t)nit * 2048;
    const unsigned short* Kp = Ks + (size_t)n * NSTRIDE + kofs + lane * 8;
    const unsigned short* Vp = Vts + (size_t)n * NSTRIDE + kofs + lane * 8;

    f32x4 oA[4], oB[4];
#pragma unroll
    for (int ct = 0; ct < 4; ++ct) { oA[ct] = f32x4{0.f, 0.f, 0.f, 0.f}; oB[ct] = oA[ct]; }

    int wr_off = (quad * 4) * 40 + m16;   // P store base (C-layout row=q, col=k)
    int rd_off = m16 * 40 + quad * 8;     // A-frag read base

    short8 kc0, kc1, kc2, kc3, vp0, vp1, vp2, vp3;

    // ---- prologue: it = 0 ----
    kc0 = *(const short8*)(Kp);
    kc1 = *(const short8*)(Kp + 512);
    kc2 = *(const short8*)(Kp + 1024);
    kc3 = *(const short8*)(Kp + 1536);
    Kp += 2048;
    vp0 = *(const short8*)(Vp);
    vp1 = *(const short8*)(Vp + 512);
    vp2 = *(const short8*)(Vp + 1024);
    vp3 = *(const short8*)(Vp + 1536);
    Vp += 2048;
    {
        f32x4 sA0 = {0.f, 0.f, 0.f, 0.f}, sA1 = sA0, sB0 = sA0, sB1 = sA0;
        sA0 = __builtin_amdgcn_mfma_f32_16x16x32_bf16(qf0, kc0, sA0, 0, 0, 0);
        sA0 = __builtin_amdgcn_mfma_f32_16x16x32_bf16(qf1, kc1, sA0, 0, 0, 0);
        sA1 = __builtin_amdgcn_mfma_f32_16x16x32_bf16(qf0, kc2, sA1, 0, 0, 0);
        sA1 = __builtin_amdgcn_mfma_f32_16x16x32_bf16(qf1, kc3, sA1, 0, 0, 0);
        sB0 = __builtin_amdgcn_mfma_f32_16x16x32_bf16(qg0, kc0, sB0, 0, 0, 0);
        sB0 = __builtin_amdgcn_mfma_f32_16x16x32_bf16(qg1, kc1, sB0, 0, 0, 0);
        sB1 = __builtin_amdgcn_mfma_f32_16x16x32_bf16(qg0, kc2, sB1, 0, 0, 0);
        sB1 = __builtin_amdgcn_mfma_f32_16x16x32_bf16(qg1, kc3, sB1, 0, 0, 0);
        short* pA = &plds[w][0][0][0][0] + wr_off;
        short* pB = &plds[w][0][1][0][0] + wr_off;
#pragma unroll
        for (int rr = 0; rr < 4; ++rr) {
            pA[rr * 40]      = (short)f2bf(fexp2(sA0[rr]));
            pA[rr * 40 + 16] = (short)f2bf(fexp2(sA1[rr]));
            pB[rr * 40]      = (short)f2bf(fexp2(sB0[rr]));
            pB[rr * 40 + 16] = (short)f2bf(fexp2(sB1[rr]));
        }
    }
    // K(1) for the first loop body
    kc0 = *(const short8*)(Kp);
    kc1 = *(const short8*)(Kp + 512);
    kc2 = *(const short8*)(Kp + 1024);
    kc3 = *(const short8*)(Kp + 1536);
    Kp += 2048;

    // ---- pipelined body: it = 1 .. nit-1 ----
    for (int it = 1; it < nit; ++it) {
        // prefetch K(it+1) (overread at it=nit-1: lands in-ws, unused)
        short8 kn0 = *(const short8*)(Kp);
        short8 kn1 = *(const short8*)(Kp + 512);
        short8 kn2 = *(const short8*)(Kp + 1024);
        short8 kn3 = *(const short8*)(Kp + 1536);
        Kp += 2048;
        // V(it): consumed next iteration
        short8 vn0 = *(const short8*)(Vp);
        short8 vn1 = *(const short8*)(Vp + 512);
        short8 vn2 = *(const short8*)(Vp + 1024);
        short8 vn3 = *(const short8*)(Vp + 1536);
        Vp += 2048;

        // S(it) for both q-tiles from kc = K(it), loaded one iteration ago
        f32x4 sA0 = {0.f, 0.f, 0.f, 0.f}, sA1 = sA0, sB0 = sA0, sB1 = sA0;
        sA0 = __builtin_amdgcn_mfma_f32_16x16x32_bf16(qf0, kc0, sA0, 0, 0, 0);
        sA0 = __builtin_amdgcn_mfma_f32_16x16x32_bf16(qf1, kc1, sA0, 0, 0, 0);
        sA1 = __builtin_amdgcn_mfma_f32_16x16x32_bf16(qf0, kc2, sA1, 0, 0, 0);
        sA1 = __builtin_amdgcn_mfma_f32_16x16x32_bf16(qf1, kc3, sA1, 0, 0, 0);
        sB0 = __builtin_amdgcn_mfma_f32_16x16x32_bf16(qg0, kc0, sB0, 0, 0, 0);
        sB0 = __builtin_amdgcn_mfma_f32_16x16x32_bf16(qg1, kc1, sB0, 0, 0, 0);
        sB1 = __builtin_amdgcn_mfma_f32_16x16x32_bf16(qg0, kc2, sB1, 0, 0, 0);
        sB1 = __builtin_amdgcn_mfma_f32_16x16x32_bf16(qg1, kc3, sB1, 0, 0, 0);

        // PV(it-1): P from LDS dbuf (written last iter), V(it-1) from registers
        {
            int pb = (it - 1) & 1;
            short8 pfA = *(const short8*)(&plds[w][pb][0][0][0] + rd_off);
            short8 pfB = *(const short8*)(&plds[w][pb][1][0][0] + rd_off);
            oA[0] = __builtin_amdgcn_mfma_f32_16x16x32_bf16(pfA, vp0, oA[0], 0, 0, 0);
            oA[1] = __builtin_amdgcn_mfma_f32_16x16x32_bf16(pfA, vp1, oA[1], 0, 0, 0);
            oA[2] = __builtin_amdgcn_mfma_f32_16x16x32_bf16(pfA, vp2, oA[2], 0, 0, 0);
            oA[3] = __builtin_amdgcn_mfma_f32_16x16x32_bf16(pfA, vp3, oA[3], 0, 0, 0);
            oB[0] = __builtin_amdgcn_mfma_f32_16x16x32_bf16(pfB, vp0, oB[0], 0, 0, 0);
            oB[1] = __builtin_amdgcn_mfma_f32_16x16x32_bf16(pfB, vp1, oB[1], 0, 0, 0);
            oB[2] = __builtin_amdgcn_mfma_f32_16x16x32_bf16(pfB, vp2, oB[2], 0, 0, 0);
            oB[3] = __builtin_amdgcn_mfma_f32_16x16x32_bf16(pfB, vp3, oB[3], 0, 0, 0);
        }

        // P(it) -> other LDS buffer, both q-tiles
        {
            int pb = it & 1;
            short* pA = &plds[w][pb][0][0][0] + wr_off;
            short* pB = &plds[w][pb][1][0][0] + wr_off;
#pragma unroll
            for (int rr = 0; rr < 4; ++rr) {
                pA[rr * 40]      = (short)f2bf(fexp2(sA0[rr]));
                pA[rr * 40 + 16] = (short)f2bf(fexp2(sA1[rr]));
                pB[rr * 40]      = (short)f2bf(fexp2(sB0[rr]));
                pB[rr * 40 + 16] = (short)f2bf(fexp2(sB1[rr]));
            }
        }

        kc0 = kn0; kc1 = kn1; kc2 = kn2; kc3 = kn3;
        vp0 = vn0; vp1 = vn1; vp2 = vn2; vp3 = vn3;
    }

    // ---- epilogue: PV for it = nit-1 ----
    {
        int pb = (nit - 1) & 1;
        short8 pfA = *(const short8*)(&plds[w][pb][0][0][0] + rd_off);
        short8 pfB = *(const short8*)(&plds[w][pb][1][0][0] + rd_off);
        oA[0] = __builtin_amdgcn_mfma_f32_16x16x32_bf16(pfA, vp0, oA[0], 0, 0, 0);
        oA[1] = __builtin_amdgcn_mfma_f32_16x16x32_bf16(pfA, vp1, oA[1], 0, 0, 0);
        oA[2] = __builtin_amdgcn_mfma_f32_16x16x32_bf16(pfA, vp2, oA[2], 0, 0, 0);
        oA[3] = __builtin_amdgcn_mfma_f32_16x16x32_bf16(pfA, vp3, oA[3], 0, 0, 0);
        oB[0] = __builtin_amdgcn_mfma_f32_16x16x32_bf16(pfB, vp0, oB[0], 0, 0, 0);
        oB[1] = __builtin_amdgcn_mfma_f32_16x16x32_bf16(pfB, vp1, oB[1], 0, 0, 0);
        oB[2] = __builtin_amdgcn_mfma_f32_16x16x32_bf16(pfB, vp2, oB[2], 0, 0, 0);
        oB[3] = __builtin_amdgcn_mfma_f32_16x16x32_bf16(pfB, vp3, oB[3], 0, 0, 0);
    }

    // store both q-tiles' partials
    float* pp = partial + (size_t)blockIdx.z * (NB * HWN * CD) +
                ((size_t)(n * HWN + qbase + quad * 4)) * CD + m16;
#pragma unroll
    for (int ct = 0; ct < 4; ++ct)
#pragma unroll
        for (int rr = 0; rr < 4; ++rr) {
            pp[rr * CD + ct * 16] = oA[ct][rr];
            pp[(64 + rr) * CD + ct * 16] = oB[ct][rr];  // +64 q rows
        }
}

// ---------- final: out = sum of ns partial slices ----------
__global__ __launch_bounds__(256) void reduce_out(const float* __restrict__ p,
                                                  float* __restrict__ out, int ns) {
    int i = (blockIdx.x * 256 + threadIdx.x) * 4;
    f32x4 a = *(const f32x4*)(p + i);
    for (int s = 1; s < ns; ++s)
        a = a + *(const f32x4*)(p + (size_t)s * (NB * HWN * CD) + i);
    *(f32x4*)(out + i) = a;
}

extern "C" void kernel_launch(void* const* d_in, const int* in_sizes, int n_in,
                              void* d_out, int out_size, void* d_ws, size_t ws_size,
                              hipStream_t stream) {
    const float* Q = (const float*)d_in[0];
    const float* K = (const float*)d_in[1];
    const float* V = (const float*)d_in[2];
    float* out = (float*)d_out;

    char* ws = (char*)d_ws;
    unsigned short* Qs  = (unsigned short*)(ws);                   // 2 MB
    unsigned short* Ks  = (unsigned short*)(ws + (1u << 21));      // 2 MB
    unsigned short* Vts = (unsigned short*)(ws + (2u << 21));      // 2 MB
    float* l       = (float*)(ws + (3u << 21));                    // 64 KB
    float* partial = (float*)(ws + (4u << 21));                    // ns * 4 MB

    size_t base = (size_t)(4u << 21);
    size_t slice = (size_t)NB * HWN * CD * sizeof(float);
    int ns = (ws_size >= base + 8 * slice) ? 8
           : (ws_size >= base + 4 * slice) ? 4 : 2;
    int nit = HWN / ns / 32;  // ns=8 -> 16 iters

    (void)hipMemsetAsync(l, 0, (size_t)NB * HWN * sizeof(float), stream);

    cvt_qk<<<1024, 256, 0, stream>>>(Q, K, Qs, Ks);
    lsum_kernel<<<dim3(16, NB, 16), 256, 0, stream>>>(Qs, Ks, l);
    prep_v<<<dim3(64, NB), 256, 0, stream>>>(V, l, Vts);
    attn_kernel<<<dim3(32, NB, ns), 256, 0, stream>>>(Qs, Ks, Vts, partial, nit);
    reduce_out<<<1024, 256, 0, stream>>>(partial, out, ns);
}